// Round 16
// baseline (172.589 us; speedup 1.0000x reference)
//
#include <hip/hip_runtime.h>
#include <hip/hip_bf16.h>
#include <cstdint>
#include <cstddef>

typedef __bf16 bf16;
typedef __bf16 bf16x8 __attribute__((ext_vector_type(8)));
typedef __bf16 bf16x4 __attribute__((ext_vector_type(4)));
typedef __bf16 bf16x2 __attribute__((ext_vector_type(2)));
typedef float  f32x4  __attribute__((ext_vector_type(4)));
typedef float  f32x16 __attribute__((ext_vector_type(16)));
typedef unsigned int u32x2 __attribute__((ext_vector_type(2)));
typedef unsigned int u32x4 __attribute__((ext_vector_type(4)));

constexpr int D_MODEL = 1024;
constexpr int TT      = 2048;   // seq len
constexpr int NBATCH  = 4;
constexpr int NH      = 16;
constexpr int QKS     = 2048;   // fused Q|K row stride
// softmax scale 1/sqrt(64) and log2(e) folded into Wq at convert time:
// Q' = x (C2*Wq)^T  ->  s' = C2*(q.k)  ->  P = exp2(s'). The missing fixed
// shift is a constant factor on all P of a row; it cancels in O = (PV)/(P1).
constexpr float C2 = 0.125f * 1.44269504088896340736f;

// ---------------- helpers ----------------
typedef const __attribute__((address_space(1))) unsigned int* gas_ptr;
typedef       __attribute__((address_space(3))) unsigned int* las_ptr;

__device__ __forceinline__ void gload_lds16(const void* g, void* l) {
  __builtin_amdgcn_global_load_lds((gas_ptr)g, (las_ptr)l, 16, 0, 0);
}

// v_permlane32_swap_b32 (builtin, compiler-modeled hazards):
// new_a = {a[0:31], b[0:31]}, new_b = {a[32:63], b[32:63]}.
__device__ __forceinline__ void permswap(unsigned int& a, unsigned int& b) {
  u32x2 r = __builtin_amdgcn_permlane32_swap(a, b, false, false);
  a = r[0]; b = r[1];
}

__device__ __forceinline__ unsigned int pk2(float a, float b) {
  bf16x2 t; t[0] = (bf16)a; t[1] = (bf16)b;
  return __builtin_bit_cast(unsigned int, t);
}

// ---------------- fused fp32 -> bf16 convert (x + all four weights) ----------
// x: 2^21 groups of 4; weights: 4 x 2^18 groups. Wq (scaled by C2),Wk -> Wqk.
__global__ void cvtall_kernel(const float* __restrict__ x,  const float* __restrict__ wq,
                              const float* __restrict__ wk, const float* __restrict__ wv,
                              const float* __restrict__ wo,
                              bf16* __restrict__ xb,  bf16* __restrict__ wqk,
                              bf16* __restrict__ wvb, bf16* __restrict__ wob) {
  const int i = blockIdx.x * 256 + threadIdx.x;
  const float* s; bf16* o; int k; float sc = 1.0f;
  if (i < (1 << 21)) {
    s = x; o = xb; k = i;
  } else {
    const int j = i - (1 << 21);
    const int g = j >> 18;
    k = j & ((1 << 18) - 1);
    s = (g == 0) ? wq : (g == 1) ? wk : (g == 2) ? wv : wo;
    o = (g == 0) ? wqk : (g == 1) ? (wqk + (1u << 20)) : (g == 2) ? wvb : wob;
    if (g == 0) sc = C2;
  }
  f32x4 v = reinterpret_cast<const f32x4*>(s)[k];
  bf16x4 t;
  t[0] = (bf16)(v[0] * sc); t[1] = (bf16)(v[1] * sc);
  t[2] = (bf16)(v[2] * sc); t[3] = (bf16)(v[3] * sc);
  reinterpret_cast<bf16x4*>(o)[k] = t;
}

// ---------------- GEMM core: C[M][N] = A[M][K] * B[N][K]^T, K=1024, BK=64 ----
// 2-barrier structure; staged tiles XOR-swizzled both sides (pre-swizzled
// global source for linear gload_lds dest + matching read-side XOR).
template<int OM>
__device__ __forceinline__
void gemm_body(const bf16* __restrict__ A, const bf16* __restrict__ B,
               void* __restrict__ C, int N, long brow, long bcol,
               bf16* At, bf16* Bt) {
  constexpr int KD = 1024;
  const int tid = threadIdx.x;
  const int w  = tid >> 6, l = tid & 63;
  const int lr = l & 15,  lh = l >> 4;
  const int wr = w >> 1,  wc = w & 1;

  f32x4 acc[4][4] = {};

  for (int kk = 0; kk < KD; kk += 64) {
    __syncthreads();
    #pragma unroll
    for (int j = 0; j < 4; ++j) {
      const int ch  = j * 256 + w * 64 + l;   // 16B chunk id, 1024 per matrix
      const int row = ch >> 3;                // 0..127
      const int c8  = (ch & 7) ^ (row & 7);   // pre-swizzled source chunk
      gload_lds16(A + (brow + row) * KD + kk + c8 * 8, At + (j * 4 + w) * 512);
      gload_lds16(B + (bcol + row) * KD + kk + c8 * 8, Bt + (j * 4 + w) * 512);
    }
    __syncthreads();

    #pragma unroll
    for (int s = 0; s < 2; ++s) {           // two K=32 sub-steps per staged tile
      bf16x8 af[4], bfr[4];
      #pragma unroll
      for (int m = 0; m < 4; ++m) {
        const int row = wr * 64 + m * 16 + lr;
        af[m] = *reinterpret_cast<const bf16x8*>(
            (const char*)At + row * 128 + ((s * 64 + lh * 16) ^ ((row & 7) << 4)));
      }
      #pragma unroll
      for (int n = 0; n < 4; ++n) {
        const int row = wc * 64 + n * 16 + lr;
        bfr[n] = *reinterpret_cast<const bf16x8*>(
            (const char*)Bt + row * 128 + ((s * 64 + lh * 16) ^ ((row & 7) << 4)));
      }
      #pragma unroll
      for (int m = 0; m < 4; ++m)
        #pragma unroll
        for (int n = 0; n < 4; ++n)
          acc[m][n] = __builtin_amdgcn_mfma_f32_16x16x32_bf16(af[m], bfr[n], acc[m][n], 0, 0, 0);
    }
  }

  #pragma unroll
  for (int m = 0; m < 4; ++m) {
    #pragma unroll
    for (int n = 0; n < 4; ++n) {
      #pragma unroll
      for (int j = 0; j < 4; ++j) {
        const long gr = brow + wr * 64 + m * 16 + lh * 4 + j;
        const long gc = bcol + wc * 64 + n * 16 + lr;
        const float v = acc[m][n][j];
        if constexpr (OM == 1) ((float*)C)[gr * (long)N + gc] = v;
        else                   ((bf16*)C)[gr * (long)N + gc] = (bf16)v;
      }
    }
  }
}

// ---- merged projection dispatch: QK (1024 blocks) + Vt (512 blocks) --------
__global__ __launch_bounds__(256, 3)
void gemm_qkv(const bf16* __restrict__ xb, const bf16* __restrict__ Wqk,
              const bf16* __restrict__ Wvb, bf16* __restrict__ QKb,
              bf16* __restrict__ VtO) {
  __shared__ __align__(16) bf16 At[128 * 64];
  __shared__ __align__(16) bf16 Bt[128 * 64];
  int bid = blockIdx.x;
  if (bid < 1024) {            // [Q'|K] = xb [C2*Wq;Wk]^T : 64 M-tiles x 16 N-tiles
    const long brow = (long)(bid & 63) * 128;
    const long bcol = (long)(bid >> 6) * 128;
    gemm_body<0>(xb, Wqk, QKb, 2048, brow, bcol, At, Bt);
  } else {                     // V^T = Wvb xb^T : 8 M-tiles x 64 N-tiles
    bid -= 1024;
    const long brow = (long)(bid & 7) * 128;
    const long bcol = (long)(bid >> 3) * 128;
    gemm_body<0>(Wvb, xb, VtO, 8192, brow, bcol, At, Bt);
  }
}

// ---- out GEMM (fp32 out) ----------------------------------------------------
__global__ __launch_bounds__(256, 3)
void gemm_out(const bf16* __restrict__ A, const bf16* __restrict__ B,
              float* __restrict__ C) {
  __shared__ __align__(16) bf16 At[128 * 64];
  __shared__ __align__(16) bf16 Bt[128 * 64];
  const long brow = (long)blockIdx.x * 128;
  const long bcol = (long)blockIdx.y * 128;
  gemm_body<1>(A, B, C, 1024, brow, bcol, At, Bt);
}

// ---------------- causal flash attention (8-wave blocks) ----------------
// 512 threads = 8 waves x 32 q-rows = 256 q-rows per block; grid (64 bh, 8).
// Same per-wave compute path as round 15 (swapped QK^T, shift-free exp2,
// cvt_pk + permlane32_swap PV). One staged K/V tile now feeds 8 waves;
// block-iteration count (barriers + staging address work) nearly halves.
// QT8 pairs blocks (by, by+4) on one CU with qt summing to 7 -> per-CU
// work balanced (36 block-iters). XCD mapping bh%8 unchanged.
__global__ __launch_bounds__(512, 2)
void flash_kernel(const bf16* __restrict__ QK, const bf16* __restrict__ Vt,
                  bf16* __restrict__ Om) {
  const int bh  = blockIdx.x;          // 0..63 ; same-bh -> same XCD (bh%8)
  constexpr int QT8[8] = {7,6,5,4,0,1,2,3};
  const int qt  = QT8[blockIdx.y];
  const int b   = bh >> 4, h = bh & 15;
  const int tid = threadIdx.x;
  const int w   = tid >> 6, l = tid & 63;
  const int l31 = l & 31;
  const int h5  = l >> 5;

  __shared__ __align__(16) bf16 Kl[2][64 * 64];      // [buf][t][dh] swizzled, 8KB each
  __shared__ __align__(16) bf16 Vl[2][64 * 64];      // [buf][dh][t] swizzled

  // Q fragments (B-operand): lane holds Q[q = base + l31][dh = k16*16 + h5*8 + e]
  bf16x8 qf[4];
  {
    const bf16* qp = QK + ((long)(b * TT + qt * 256 + w * 32 + l31)) * QKS + h * 64 + h5 * 8;
    #pragma unroll
    for (int k16 = 0; k16 < 4; ++k16)
      qf[k16] = *reinterpret_cast<const bf16x8*>(qp + k16 * 16);
  }

  f32x16 acc[2] = {};   // [db]: O[q=(r&3)+8*(r>>2)+4*h5][d=db*32+l31]
  float  lp = 0.f;

  // hoisted fragment byte-offsets (lane-dependent, loop-invariant)
  int koff[2][4], voff[4][2];
  #pragma unroll
  for (int kb = 0; kb < 2; ++kb) {
    const int row = kb * 32 + l31;
    #pragma unroll
    for (int k16 = 0; k16 < 4; ++k16)
      koff[kb][k16] = row * 128 + ((k16 * 32 + h5 * 16) ^ ((row & 7) << 4));
  }
  #pragma unroll
  for (int db = 0; db < 2; ++db) {
    const int row = db * 32 + l31;
    #pragma unroll
    for (int k4 = 0; k4 < 4; ++k4)
      voff[k4][db] = row * 128 + ((k4 * 32 + h5 * 16) ^ ((row & 7) << 4));
  }

  // staging: 512 16B-chunks per 64x64 tile; thread tid owns chunk tid.
  auto stage = [&](int kt, int p) {
    const int r = tid >> 3;
    const int c = (tid & 7) ^ (r & 7);
    gload_lds16(QK + ((long)(b * TT + kt * 64 + r)) * QKS + 1024 + h * 64 + c * 8,
                (bf16*)Kl[p] + w * 512);
    gload_lds16(Vt + ((long)(h * 64 + r)) * (NBATCH * TT) + b * TT + kt * 64 + c * 8,
                (bf16*)Vl[p] + w * 512);
  };

  const int NT = 4 * qt + 4;
  stage(0, 0);
  __syncthreads();
  int cur = 0;

  const int wq0 = qt * 256 + w * 32;       // wave's first q-row
  const int qrow = wq0 + l31;

  for (int kt = 0; kt < NT; ++kt) {
    if (kt + 1 < NT) stage(kt + 1, cur ^ 1);   // prefetch next tile into other buf

    const char* kbase = (const char*)Kl[cur];
    const char* vbase = (const char*)Vl[cur];

    if (kt * 64 <= wq0 + 31) {               // tile not fully masked for this wave
      const bool diag = (kt * 64 + 63 > wq0);

      bf16x8 kf[2][4];
      #pragma unroll
      for (int kb = 0; kb < 2; ++kb)
        #pragma unroll
        for (int k16 = 0; k16 < 4; ++k16)
          kf[kb][k16] = *reinterpret_cast<const bf16x8*>(kbase + koff[kb][k16]);

      // S^T = K Q^T : lane holds S[kv = kb*32 + (r&3)+8*(r>>2)+4*h5][q = l31]
      f32x16 s[2] = {};
      #pragma unroll
      for (int kb = 0; kb < 2; ++kb)
        #pragma unroll
        for (int k16 = 0; k16 < 4; ++k16)
          s[kb] = __builtin_amdgcn_mfma_f32_32x32x16_bf16(kf[kb][k16], qf[k16], s[kb], 0, 0, 0);

      float lsum = 0.f;
      unsigned int W[2][8];   // W[kb][pr]: kv = kb*32 + 8*(pr>>1) + 2*(pr&1) + 4*h5 + {0,1}
      #pragma unroll
      for (int kb = 0; kb < 2; ++kb) {
        #pragma unroll
        for (int pr = 0; pr < 8; ++pr) {
          const int r0 = 2 * pr;
          float p0 = __builtin_exp2f(s[kb][r0]);       // scale pre-folded into Wq
          float p1 = __builtin_exp2f(s[kb][r0 + 1]);
          if (diag) {
            const int kv0 = kt * 64 + kb * 32 + (r0 & 3) + 8 * (r0 >> 2) + 4 * h5;
            if (kv0     > qrow) p0 = 0.f;
            if (kv0 + 1 > qrow) p1 = 0.f;
          }
          lsum += p0 + p1;
          W[kb][pr] = pk2(p0, p1);
        }
      }
      lp += lsum;

      // V fragments loaded after softmax (s dead -> lower peak VGPR)
      bf16x8 vf[4][2];
      #pragma unroll
      for (int k4 = 0; k4 < 4; ++k4)
        #pragma unroll
        for (int db = 0; db < 2; ++db)
          vf[k4][db] = *reinterpret_cast<const bf16x8*>(vbase + voff[k4][db]);

      // PV: pa[k4] = P[q = l31][kv = k4*16 + h5*8 + {0..7}] via permlane32_swap
      #pragma unroll
      for (int k4 = 0; k4 < 4; ++k4) {
        const int kb = k4 >> 1, u = (k4 & 1) * 4;
        unsigned int a0 = W[kb][u + 0], b0 = W[kb][u + 2];
        unsigned int a1 = W[kb][u + 1], b1 = W[kb][u + 3];
        permswap(a0, b0);
        permswap(a1, b1);
        u32x4 paw; paw[0] = a0; paw[1] = a1; paw[2] = b0; paw[3] = b1;
        const bf16x8 pa = __builtin_bit_cast(bf16x8, paw);
        #pragma unroll
        for (int db = 0; db < 2; ++db)
          acc[db] = __builtin_amdgcn_mfma_f32_32x32x16_bf16(pa, vf[k4][db], acc[db], 0, 0, 0);
      }
    }

    __syncthreads();   // buf cur fully read; buf cur^1 staged
    cur ^= 1;
  }

  // ---- epilogue: reduce deferred l (lane + partner hold halves of row l31), write O
  {
    float v = lp;
    v += __shfl_xor(v, 32, 64);
    const float li = 1.0f / v;        // denominator for q-row l31 (both halves agree)
    #pragma unroll
    for (int r = 0; r < 16; ++r) {
      const int qloc = (r & 3) + 8 * (r >> 2) + 4 * h5;
      const float liw = __shfl(li, qloc, 64);
      const long row = (long)(b * TT + qt * 256 + w * 32 + qloc);
      #pragma unroll
      for (int db = 0; db < 2; ++db)
        Om[row * D_MODEL + h * 64 + db * 32 + l31] = (bf16)(acc[db][r] * liw);
    }
  }
}

// ---------------- host ----------------
extern "C" void kernel_launch(void* const* d_in, const int* in_sizes, int n_in,
                              void* d_out, int out_size, void* d_ws, size_t ws_size,
                              hipStream_t stream) {
  (void)in_sizes; (void)n_in; (void)out_size; (void)ws_size;
  const float* x  = (const float*)d_in[0];
  const float* Wq = (const float*)d_in[1];
  const float* Wk = (const float*)d_in[2];
  const float* Wv = (const float*)d_in[3];
  const float* Wo = (const float*)d_in[4];

  char* ws = (char*)d_ws;
  bf16* xb  = (bf16*)(ws);                       // 16 MB: x bf16 [8192][1024]
  bf16* Wqk = (bf16*)(ws + (16u << 20));         // 4 MB: [C2*Wq;Wk] [2048][1024]
  bf16* Wvb = (bf16*)(ws + (20u << 20));         // 2 MB
  bf16* Wob = (bf16*)(ws + (22u << 20));         // 2 MB
  bf16* Vt  = (bf16*)(ws + (24u << 20));         // 16 MB: V^T [1024][8192]
  bf16* Mrg = (bf16*)(ws + (40u << 20));         // 16 MB: attention out [8192][1024]
  // fused Q'|K bf16 [8192][2048] (32 MB) lives in d_out; overwritten by final GEMM.
  bf16* QKb = (bf16*)d_out;

  // fused convert: x (2^21 f32x4 groups) + 4 weights (4 * 2^18 groups)
  cvtall_kernel<<<(3u << 20) / 256 * 1, 256, 0, stream>>>(x, Wq, Wk, Wv, Wo,
                                                          xb, Wqk, Wvb, Wob);

  // merged: [Q'|K] = xb [C2*Wq;Wk]^T (1024 blocks)  +  V^T = Wvb xb^T (512 blocks)
  gemm_qkv<<<1536, 256, 0, stream>>>(xb, Wqk, Wvb, QKb, Vt);

  flash_kernel<<<dim3(NBATCH * NH, 8), 512, 0, stream>>>(QKb, Vt, Mrg);

  // out = merged Wo^T : fp32 [8192][1024]
  gemm_out<<<dim3(64, 8), 256, 0, stream>>>(Mrg, Wob, (float*)d_out);
}

// Round 17
// 161.429 us; speedup vs baseline: 1.0691x; 1.0691x over previous
//
#include <hip/hip_runtime.h>
#include <hip/hip_bf16.h>
#include <cstdint>
#include <cstddef>

typedef __bf16 bf16;
typedef __bf16 bf16x8 __attribute__((ext_vector_type(8)));
typedef __bf16 bf16x4 __attribute__((ext_vector_type(4)));
typedef __bf16 bf16x2 __attribute__((ext_vector_type(2)));
typedef float  f32x4  __attribute__((ext_vector_type(4)));
typedef float  f32x16 __attribute__((ext_vector_type(16)));
typedef unsigned int u32x2 __attribute__((ext_vector_type(2)));
typedef unsigned int u32x4 __attribute__((ext_vector_type(4)));

constexpr int D_MODEL = 1024;
constexpr int TT      = 2048;   // seq len
constexpr int NBATCH  = 4;
constexpr int NH      = 16;
constexpr int QKS     = 2048;   // fused Q|K row stride
// softmax scale 1/sqrt(64) and log2(e) folded into Wq at convert time:
// Q' = x (C2*Wq)^T  ->  s' = C2*(q.k)  ->  P = exp2(s'). The missing fixed
// shift is a constant factor on all P of a row; it cancels in O = (PV)/(P1).
constexpr float C2 = 0.125f * 1.44269504088896340736f;

// ---------------- helpers ----------------
typedef const __attribute__((address_space(1))) unsigned int* gas_ptr;
typedef       __attribute__((address_space(3))) unsigned int* las_ptr;

__device__ __forceinline__ void gload_lds16(const void* g, void* l) {
  __builtin_amdgcn_global_load_lds((gas_ptr)g, (las_ptr)l, 16, 0, 0);
}

// v_permlane32_swap_b32 (builtin, compiler-modeled hazards):
// new_a = {a[0:31], b[0:31]}, new_b = {a[32:63], b[32:63]}.
__device__ __forceinline__ void permswap(unsigned int& a, unsigned int& b) {
  u32x2 r = __builtin_amdgcn_permlane32_swap(a, b, false, false);
  a = r[0]; b = r[1];
}

__device__ __forceinline__ unsigned int pk2(float a, float b) {
  bf16x2 t; t[0] = (bf16)a; t[1] = (bf16)b;
  return __builtin_bit_cast(unsigned int, t);
}

// ---------------- fused fp32 -> bf16 convert (x + all four weights) ----------
// x: 2^21 groups of 4; weights: 4 x 2^18 groups. Wq (scaled by C2),Wk -> Wqk.
__global__ void cvtall_kernel(const float* __restrict__ x,  const float* __restrict__ wq,
                              const float* __restrict__ wk, const float* __restrict__ wv,
                              const float* __restrict__ wo,
                              bf16* __restrict__ xb,  bf16* __restrict__ wqk,
                              bf16* __restrict__ wvb, bf16* __restrict__ wob) {
  const int i = blockIdx.x * 256 + threadIdx.x;
  const float* s; bf16* o; int k; float sc = 1.0f;
  if (i < (1 << 21)) {
    s = x; o = xb; k = i;
  } else {
    const int j = i - (1 << 21);
    const int g = j >> 18;
    k = j & ((1 << 18) - 1);
    s = (g == 0) ? wq : (g == 1) ? wk : (g == 2) ? wv : wo;
    o = (g == 0) ? wqk : (g == 1) ? (wqk + (1u << 20)) : (g == 2) ? wvb : wob;
    if (g == 0) sc = C2;
  }
  f32x4 v = reinterpret_cast<const f32x4*>(s)[k];
  bf16x4 t;
  t[0] = (bf16)(v[0] * sc); t[1] = (bf16)(v[1] * sc);
  t[2] = (bf16)(v[2] * sc); t[3] = (bf16)(v[3] * sc);
  reinterpret_cast<bf16x4*>(o)[k] = t;
}

// ---------------- GEMM core: C[M][N] = A[M][K] * B[N][K]^T, K=1024, BK=64 ----
// 2-barrier structure; staged tiles XOR-swizzled both sides (pre-swizzled
// global source for linear gload_lds dest + matching read-side XOR).
template<int OM>
__device__ __forceinline__
void gemm_body(const bf16* __restrict__ A, const bf16* __restrict__ B,
               void* __restrict__ C, int N, long brow, long bcol,
               bf16* At, bf16* Bt) {
  constexpr int KD = 1024;
  const int tid = threadIdx.x;
  const int w  = tid >> 6, l = tid & 63;
  const int lr = l & 15,  lh = l >> 4;
  const int wr = w >> 1,  wc = w & 1;

  f32x4 acc[4][4] = {};

  for (int kk = 0; kk < KD; kk += 64) {
    __syncthreads();
    #pragma unroll
    for (int j = 0; j < 4; ++j) {
      const int ch  = j * 256 + w * 64 + l;   // 16B chunk id, 1024 per matrix
      const int row = ch >> 3;                // 0..127
      const int c8  = (ch & 7) ^ (row & 7);   // pre-swizzled source chunk
      gload_lds16(A + (brow + row) * KD + kk + c8 * 8, At + (j * 4 + w) * 512);
      gload_lds16(B + (bcol + row) * KD + kk + c8 * 8, Bt + (j * 4 + w) * 512);
    }
    __syncthreads();

    #pragma unroll
    for (int s = 0; s < 2; ++s) {           // two K=32 sub-steps per staged tile
      bf16x8 af[4], bfr[4];
      #pragma unroll
      for (int m = 0; m < 4; ++m) {
        const int row = wr * 64 + m * 16 + lr;
        af[m] = *reinterpret_cast<const bf16x8*>(
            (const char*)At + row * 128 + ((s * 64 + lh * 16) ^ ((row & 7) << 4)));
      }
      #pragma unroll
      for (int n = 0; n < 4; ++n) {
        const int row = wc * 64 + n * 16 + lr;
        bfr[n] = *reinterpret_cast<const bf16x8*>(
            (const char*)Bt + row * 128 + ((s * 64 + lh * 16) ^ ((row & 7) << 4)));
      }
      #pragma unroll
      for (int m = 0; m < 4; ++m)
        #pragma unroll
        for (int n = 0; n < 4; ++n)
          acc[m][n] = __builtin_amdgcn_mfma_f32_16x16x32_bf16(af[m], bfr[n], acc[m][n], 0, 0, 0);
    }
  }

  #pragma unroll
  for (int m = 0; m < 4; ++m) {
    #pragma unroll
    for (int n = 0; n < 4; ++n) {
      #pragma unroll
      for (int j = 0; j < 4; ++j) {
        const long gr = brow + wr * 64 + m * 16 + lh * 4 + j;
        const long gc = bcol + wc * 64 + n * 16 + lr;
        const float v = acc[m][n][j];
        if constexpr (OM == 1) ((float*)C)[gr * (long)N + gc] = v;
        else                   ((bf16*)C)[gr * (long)N + gc] = (bf16)v;
      }
    }
  }
}

// ---- merged projection dispatch: QK (1024 blocks) + Vt (512 blocks) --------
__global__ __launch_bounds__(256, 3)
void gemm_qkv(const bf16* __restrict__ xb, const bf16* __restrict__ Wqk,
              const bf16* __restrict__ Wvb, bf16* __restrict__ QKb,
              bf16* __restrict__ VtO) {
  __shared__ __align__(16) bf16 At[128 * 64];
  __shared__ __align__(16) bf16 Bt[128 * 64];
  int bid = blockIdx.x;
  if (bid < 1024) {            // [Q'|K] = xb [C2*Wq;Wk]^T : 64 M-tiles x 16 N-tiles
    const long brow = (long)(bid & 63) * 128;
    const long bcol = (long)(bid >> 6) * 128;
    gemm_body<0>(xb, Wqk, QKb, 2048, brow, bcol, At, Bt);
  } else {                     // V^T = Wvb xb^T : 8 M-tiles x 64 N-tiles
    bid -= 1024;
    const long brow = (long)(bid & 7) * 128;
    const long bcol = (long)(bid >> 3) * 128;
    gemm_body<0>(Wvb, xb, VtO, 8192, brow, bcol, At, Bt);
  }
}

// ---- out GEMM (fp32 out) ----------------------------------------------------
__global__ __launch_bounds__(256, 3)
void gemm_out(const bf16* __restrict__ A, const bf16* __restrict__ B,
              float* __restrict__ C) {
  __shared__ __align__(16) bf16 At[128 * 64];
  __shared__ __align__(16) bf16 Bt[128 * 64];
  const long brow = (long)blockIdx.x * 128;
  const long bcol = (long)blockIdx.y * 128;
  gemm_body<1>(A, B, C, 1024, brow, bcol, At, Bt);
}

// ---------------- causal flash attention ----------------
// Round-15 known-good: one q-tile (128 rows) per block, 4 waves x 32 rows,
// grid (64 bh, 16). Softmax is exactly one v_exp2 per element (scale
// pre-folded into Wq, shift-free: constant factor cancels in normalization).
// QT Latin square balances per-CU kv-iteration totals (=68).
__global__ __launch_bounds__(256, 4)
void flash_kernel(const bf16* __restrict__ QK, const bf16* __restrict__ Vt,
                  bf16* __restrict__ Om) {
  const int bh  = blockIdx.x;          // 0..63 ; same-bh -> same XCD (bh%8)
  constexpr int QT[4][4] = {{15,14,13,12},{8,9,10,11},{7,6,5,4},{0,1,2,3}};
  const int qt  = QT[blockIdx.y >> 2][blockIdx.y & 3];
  const int b   = bh >> 4, h = bh & 15;
  const int tid = threadIdx.x;
  const int w   = tid >> 6, l = tid & 63;
  const int l31 = l & 31;
  const int h5  = l >> 5;

  __shared__ __align__(16) bf16 Kl[2][64 * 64];      // [buf][t][dh] swizzled, 8KB each
  __shared__ __align__(16) bf16 Vl[2][64 * 64];      // [buf][dh][t] swizzled

  // Q fragments (B-operand): lane holds Q[q = base + l31][dh = k16*16 + h5*8 + e]
  bf16x8 qf[4];
  {
    const bf16* qp = QK + ((long)(b * TT + qt * 128 + w * 32 + l31)) * QKS + h * 64 + h5 * 8;
    #pragma unroll
    for (int k16 = 0; k16 < 4; ++k16)
      qf[k16] = *reinterpret_cast<const bf16x8*>(qp + k16 * 16);
  }

  f32x16 acc[2] = {};   // [db]: O[q=(r&3)+8*(r>>2)+4*h5][d=db*32+l31]
  float  lp = 0.f;

  // hoisted fragment byte-offsets (lane-dependent, loop-invariant)
  int koff[2][4], voff[4][2];
  #pragma unroll
  for (int kb = 0; kb < 2; ++kb) {
    const int row = kb * 32 + l31;
    #pragma unroll
    for (int k16 = 0; k16 < 4; ++k16)
      koff[kb][k16] = row * 128 + ((k16 * 32 + h5 * 16) ^ ((row & 7) << 4));
  }
  #pragma unroll
  for (int db = 0; db < 2; ++db) {
    const int row = db * 32 + l31;
    #pragma unroll
    for (int k4 = 0; k4 < 4; ++k4)
      voff[k4][db] = row * 128 + ((k4 * 32 + h5 * 16) ^ ((row & 7) << 4));
  }

  auto stage = [&](int kt, int p) {
    #pragma unroll
    for (int i = 0; i < 2; ++i) {
      const int ch = i * 256 + w * 64 + l;
      const int r  = ch >> 3;
      const int c  = (ch & 7) ^ (r & 7);
      gload_lds16(QK + ((long)(b * TT + kt * 64 + r)) * QKS + 1024 + h * 64 + c * 8,
                  (bf16*)Kl[p] + (i * 4 + w) * 512);
      gload_lds16(Vt + ((long)(h * 64 + r)) * (NBATCH * TT) + b * TT + kt * 64 + c * 8,
                  (bf16*)Vl[p] + (i * 4 + w) * 512);
    }
  };

  const int NT = 2 * qt + 2;
  stage(0, 0);
  __syncthreads();
  int cur = 0;

  const int wq0 = qt * 128 + w * 32;       // wave's first q-row
  const int qrow = wq0 + l31;

  for (int kt = 0; kt < NT; ++kt) {
    if (kt + 1 < NT) stage(kt + 1, cur ^ 1);   // prefetch next tile into other buf

    const char* kbase = (const char*)Kl[cur];
    const char* vbase = (const char*)Vl[cur];

    if (kt * 64 <= wq0 + 31) {               // tile not fully masked for this wave
      const bool diag = (kt * 64 + 63 > wq0);

      bf16x8 kf[2][4];
      #pragma unroll
      for (int kb = 0; kb < 2; ++kb)
        #pragma unroll
        for (int k16 = 0; k16 < 4; ++k16)
          kf[kb][k16] = *reinterpret_cast<const bf16x8*>(kbase + koff[kb][k16]);

      // S^T = K Q^T : lane holds S[kv = kb*32 + (r&3)+8*(r>>2)+4*h5][q = l31]
      f32x16 s[2] = {};
      #pragma unroll
      for (int kb = 0; kb < 2; ++kb)
        #pragma unroll
        for (int k16 = 0; k16 < 4; ++k16)
          s[kb] = __builtin_amdgcn_mfma_f32_32x32x16_bf16(kf[kb][k16], qf[k16], s[kb], 0, 0, 0);

      float lsum = 0.f;
      unsigned int W[2][8];   // W[kb][pr]: kv = kb*32 + 8*(pr>>1) + 2*(pr&1) + 4*h5 + {0,1}
      #pragma unroll
      for (int kb = 0; kb < 2; ++kb) {
        #pragma unroll
        for (int pr = 0; pr < 8; ++pr) {
          const int r0 = 2 * pr;
          float p0 = __builtin_exp2f(s[kb][r0]);       // scale pre-folded into Wq
          float p1 = __builtin_exp2f(s[kb][r0 + 1]);
          if (diag) {
            const int kv0 = kt * 64 + kb * 32 + (r0 & 3) + 8 * (r0 >> 2) + 4 * h5;
            if (kv0     > qrow) p0 = 0.f;
            if (kv0 + 1 > qrow) p1 = 0.f;
          }
          lsum += p0 + p1;
          W[kb][pr] = pk2(p0, p1);
        }
      }
      lp += lsum;

      // V fragments loaded after softmax (s dead -> lower peak VGPR)
      bf16x8 vf[4][2];
      #pragma unroll
      for (int k4 = 0; k4 < 4; ++k4)
        #pragma unroll
        for (int db = 0; db < 2; ++db)
          vf[k4][db] = *reinterpret_cast<const bf16x8*>(vbase + voff[k4][db]);

      // PV: pa[k4] = P[q = l31][kv = k4*16 + h5*8 + {0..7}] via permlane32_swap
      #pragma unroll
      for (int k4 = 0; k4 < 4; ++k4) {
        const int kb = k4 >> 1, u = (k4 & 1) * 4;
        unsigned int a0 = W[kb][u + 0], b0 = W[kb][u + 2];
        unsigned int a1 = W[kb][u + 1], b1 = W[kb][u + 3];
        permswap(a0, b0);
        permswap(a1, b1);
        u32x4 paw; paw[0] = a0; paw[1] = a1; paw[2] = b0; paw[3] = b1;
        const bf16x8 pa = __builtin_bit_cast(bf16x8, paw);
        #pragma unroll
        for (int db = 0; db < 2; ++db)
          acc[db] = __builtin_amdgcn_mfma_f32_32x32x16_bf16(pa, vf[k4][db], acc[db], 0, 0, 0);
      }
    }

    __syncthreads();   // buf cur fully read; buf cur^1 staged
    cur ^= 1;
  }

  // ---- epilogue: reduce deferred l (lane + partner hold halves of row l31), write O
  {
    float v = lp;
    v += __shfl_xor(v, 32, 64);
    const float li = 1.0f / v;        // denominator for q-row l31 (both halves agree)
    #pragma unroll
    for (int r = 0; r < 16; ++r) {
      const int qloc = (r & 3) + 8 * (r >> 2) + 4 * h5;
      const float liw = __shfl(li, qloc, 64);
      const long row = (long)(b * TT + qt * 128 + w * 32 + qloc);
      #pragma unroll
      for (int db = 0; db < 2; ++db)
        Om[row * D_MODEL + h * 64 + db * 32 + l31] = (bf16)(acc[db][r] * liw);
    }
  }
}

// ---------------- host ----------------
extern "C" void kernel_launch(void* const* d_in, const int* in_sizes, int n_in,
                              void* d_out, int out_size, void* d_ws, size_t ws_size,
                              hipStream_t stream) {
  (void)in_sizes; (void)n_in; (void)out_size; (void)ws_size;
  const float* x  = (const float*)d_in[0];
  const float* Wq = (const float*)d_in[1];
  const float* Wk = (const float*)d_in[2];
  const float* Wv = (const float*)d_in[3];
  const float* Wo = (const float*)d_in[4];

  char* ws = (char*)d_ws;
  bf16* xb  = (bf16*)(ws);                       // 16 MB: x bf16 [8192][1024]
  bf16* Wqk = (bf16*)(ws + (16u << 20));         // 4 MB: [C2*Wq;Wk] [2048][1024]
  bf16* Wvb = (bf16*)(ws + (20u << 20));         // 2 MB
  bf16* Wob = (bf16*)(ws + (22u << 20));         // 2 MB
  bf16* Vt  = (bf16*)(ws + (24u << 20));         // 16 MB: V^T [1024][8192]
  bf16* Mrg = (bf16*)(ws + (40u << 20));         // 16 MB: attention out [8192][1024]
  // fused Q'|K bf16 [8192][2048] (32 MB) lives in d_out; overwritten by final GEMM.
  bf16* QKb = (bf16*)d_out;

  // fused convert: x (2^21 f32x4 groups) + 4 weights (4 * 2^18 groups)
  cvtall_kernel<<<(3u << 20) / 256 * 1, 256, 0, stream>>>(x, Wq, Wk, Wv, Wo,
                                                          xb, Wqk, Wvb, Wob);

  // merged: [Q'|K] = xb [C2*Wq;Wk]^T (1024 blocks)  +  V^T = Wvb xb^T (512 blocks)
  gemm_qkv<<<1536, 256, 0, stream>>>(xb, Wqk, Wvb, QKb, Vt);

  flash_kernel<<<dim3(NBATCH * NH, 16), 256, 0, stream>>>(QKb, Vt, Mrg);

  // out = merged Wo^T : fp32 [8192][1024]
  gemm_out<<<dim3(64, 8), 256, 0, stream>>>(Mrg, Wob, (float*)d_out);
}